// Round 14
// baseline (224.323 us; speedup 1.0000x reference)
//
#include <hip/hip_runtime.h>
#include <hip/hip_bf16.h>

// ============================================================================
// R14 = R13 (passed, 215.1us — session best) + register-fitting pipelined
//       256-core for s_exp (single delta).
//
// R10 diagnosis refined: its pipelined-256 carried TWO B-sets across the
// tile boundary (bfaP+bfaQ = 112 VGPR fragments) -> +addr +128 AGPR > 256
// unified budget -> thrash (VGPR pinned 128, MfmaUtil 21%). Fix: quadrant
// rotation — C2 runs Q10(afQ,bfa) so bfa is DEAD at C3, which overwrites
// bfa with tile t+1's b-half-0 while running Q11(afQ,bfb). Fragment peak
// 96 VGPR (+addr ~116, +128 AGPR = 244 <= 256). Ledger identical to the
// HW-passed R10 core (vm8 prologue, counted vm4, same WAR chain).
// Numerics: per-acc-element k-order unchanged (quadrants are disjoint acc
// elements) -> bitwise identical. Everything else = R13.
// ============================================================================

// ---------- types ----------
typedef __attribute__((ext_vector_type(8))) short short8;   // 8 x bf16 (4 VGPRs)
typedef __attribute__((ext_vector_type(4))) float f32x4;    // 16x16 MFMA accumulator

typedef unsigned short u16;

__device__ __forceinline__ u16 f32_to_bf16(float f) {
    unsigned int u = __float_as_uint(f);
    u += 0x7fffu + ((u >> 16) & 1u);   // round-to-nearest-even
    return (u16)(u >> 16);
}

// async global->LDS, 16B per lane; LDS dest = wave-uniform base + lane*16
__device__ __forceinline__ void gload16(const u16* g, u16* lds_base) {
    __builtin_amdgcn_global_load_lds(
        (const __attribute__((address_space(1))) void*)g,
        (__attribute__((address_space(3))) void*)lds_base, 16, 0, 0);
}

__device__ __forceinline__ void bar() { __builtin_amdgcn_s_barrier(); }
__device__ __forceinline__ void bar_end() {
    __builtin_amdgcn_sched_barrier(0);
    __builtin_amdgcn_s_barrier();
}
__device__ __forceinline__ void wait_vm8() {
    asm volatile("s_waitcnt vmcnt(8)" ::: "memory");
}
__device__ __forceinline__ void wait_vm7() {
    asm volatile("s_waitcnt vmcnt(7)" ::: "memory");
}
__device__ __forceinline__ void wait_vm6() {
    asm volatile("s_waitcnt vmcnt(6)" ::: "memory");
}
__device__ __forceinline__ void wait_vm4() {
    asm volatile("s_waitcnt vmcnt(4)" ::: "memory");
}
__device__ __forceinline__ void wait_vm3() {
    asm volatile("s_waitcnt vmcnt(3)" ::: "memory");
}
__device__ __forceinline__ void wait_vm2() {
    asm volatile("s_waitcnt vmcnt(2)" ::: "memory");
}
__device__ __forceinline__ void wait_vm0() {
    asm volatile("s_waitcnt vmcnt(0)" ::: "memory");
}

// ---------- fused input cast + l-zero: x then W fp32->bf16, then l=0 --------
__global__ void cast_inputs(const float* __restrict__ x, u16* __restrict__ Xb,
                            const float* __restrict__ W, u16* __restrict__ Wb,
                            float* __restrict__ l,
                            int nx4, int nw4, int nl) {
    int i = blockIdx.x * blockDim.x + threadIdx.x;
    if (i >= nx4 + nw4) {                 // tail blocks: zero softmax denom
        int idx = i - (nx4 + nw4);
        if (idx < nl) l[idx] = 0.f;
        return;
    }
    const float* in; u16* out; int idx;
    if (i < nx4) { in = x; out = Xb; idx = i; }
    else { idx = i - nx4; in = W; out = Wb; }
    float4 v = ((const float4*)in)[idx];
    ushort4 o;
    o.x = f32_to_bf16(v.x); o.y = f32_to_bf16(v.y);
    o.z = f32_to_bf16(v.z); o.w = f32_to_bf16(v.w);
    ((ushort4*)out)[idx] = o;
}

// ============================================================================
// GEMM cores.
//  * 256x192 (gemm_core_192): 4-cluster pipelined (R6 HW-pass). qkv, linear.
//  * 256x256 (gemm_core_256): R14 pipelined, single-buffered bfa (above).
//  * 256x128 (gemm_core_n128): 4-cluster pipelined (R11 HW-pass). pv, chunked.
// ============================================================================

struct Acc256 { f32x4 acc[8][4]; };
struct Acc192 { f32x4 acc[8][3]; };
struct Acc128 { f32x4 acc[8][2]; };

template<int MH>
__device__ __forceinline__ void rd_a(const u16* __restrict__ sA, int wr, int lane,
                                     int lr, short8 (&af)[4][2]) {
#pragma unroll
    for (int a2 = 0; a2 < 4; ++a2) {
        const int row = wr * 128 + MH * 64 + a2 * 16 + lr;
#pragma unroll
        for (int k2 = 0; k2 < 2; ++k2) {
            const int cb = (lane >> 4) + k2 * 4;
            af[a2][k2] = *(const short8*)(sA + row * 64 + ((cb ^ (lr & 7)) * 8));
        }
    }
}

// ---- 256-wide B helpers (s_exp core) ----
template<int NH>
__device__ __forceinline__ void rd_b(const u16* __restrict__ sB, int wc, int lane,
                                     int lr, short8 (&bf)[2][2]) {
#pragma unroll
    for (int b2 = 0; b2 < 2; ++b2) {
        const int row = wc * 64 + NH * 32 + b2 * 16 + lr;
#pragma unroll
        for (int k2 = 0; k2 < 2; ++k2) {
            const int cb = (lane >> 4) + k2 * 4;
            bf[b2][k2] = *(const short8*)(sB + row * 64 + ((cb ^ (lr & 7)) * 8));
        }
    }
}

template<int MH, int NH>
__device__ __forceinline__ void mm_q(Acc256& fr, const short8 (&af)[4][2],
                                     const short8 (&bf)[2][2]) {
    __builtin_amdgcn_s_setprio(1);
#pragma unroll
    for (int a2 = 0; a2 < 4; ++a2)
#pragma unroll
        for (int b2 = 0; b2 < 2; ++b2)
#pragma unroll
            for (int k2 = 0; k2 < 2; ++k2)
                fr.acc[MH * 4 + a2][NH * 2 + b2] =
                    __builtin_amdgcn_mfma_f32_16x16x32_bf16(
                        af[a2][k2], bf[b2][k2],
                        fr.acc[MH * 4 + a2][NH * 2 + b2], 0, 0, 0);
    __builtin_amdgcn_s_setprio(0);
}

// ---- 192-wide B helpers (qkv core) ----
__device__ __forceinline__ void rd_b01(const u16* __restrict__ sB, int wc, int lane,
                                       int lr, short8 (&bf)[2][2]) {
#pragma unroll
    for (int b2 = 0; b2 < 2; ++b2) {
        const int row = wc * 48 + b2 * 16 + lr;
#pragma unroll
        for (int k2 = 0; k2 < 2; ++k2) {
            const int cb = (lane >> 4) + k2 * 4;
            bf[b2][k2] = *(const short8*)(sB + row * 64 + ((cb ^ (lr & 7)) * 8));
        }
    }
}

__device__ __forceinline__ void rd_b2(const u16* __restrict__ sB, int wc, int lane,
                                      int lr, short8 (&bf)[2]) {
    const int row = wc * 48 + 32 + lr;
#pragma unroll
    for (int k2 = 0; k2 < 2; ++k2) {
        const int cb = (lane >> 4) + k2 * 4;
        bf[k2] = *(const short8*)(sB + row * 64 + ((cb ^ (lr & 7)) * 8));
    }
}

template<int MH>
__device__ __forceinline__ void mm_b01(Acc192& fr, const short8 (&af)[4][2],
                                       const short8 (&bf)[2][2]) {
    __builtin_amdgcn_s_setprio(1);
#pragma unroll
    for (int a2 = 0; a2 < 4; ++a2)
#pragma unroll
        for (int b2 = 0; b2 < 2; ++b2)
#pragma unroll
            for (int k2 = 0; k2 < 2; ++k2)
                fr.acc[MH * 4 + a2][b2] =
                    __builtin_amdgcn_mfma_f32_16x16x32_bf16(
                        af[a2][k2], bf[b2][k2],
                        fr.acc[MH * 4 + a2][b2], 0, 0, 0);
    __builtin_amdgcn_s_setprio(0);
}

template<int MH>
__device__ __forceinline__ void mm_b2(Acc192& fr, const short8 (&af)[4][2],
                                      const short8 (&bf)[2]) {
    __builtin_amdgcn_s_setprio(1);
#pragma unroll
    for (int a2 = 0; a2 < 4; ++a2)
#pragma unroll
        for (int k2 = 0; k2 < 2; ++k2)
            fr.acc[MH * 4 + a2][2] =
                __builtin_amdgcn_mfma_f32_16x16x32_bf16(
                    af[a2][k2], bf[k2], fr.acc[MH * 4 + a2][2], 0, 0, 0);
    __builtin_amdgcn_s_setprio(0);
}

// ---- 128-wide B helpers (pv core): single-fragment b0 / b1 reads ----
template<int BI>
__device__ __forceinline__ void rd_b1f(const u16* __restrict__ sB, int wc, int lane,
                                       int lr, short8 (&bf)[2]) {
    const int row = wc * 32 + BI * 16 + lr;
#pragma unroll
    for (int k2 = 0; k2 < 2; ++k2) {
        const int cb = (lane >> 4) + k2 * 4;
        bf[k2] = *(const short8*)(sB + row * 64 + ((cb ^ (lr & 7)) * 8));
    }
}

template<int MH, int BI>
__device__ __forceinline__ void mm_h(Acc128& fr, const short8 (&af)[4][2],
                                     const short8 (&bf)[2]) {
    __builtin_amdgcn_s_setprio(1);
#pragma unroll
    for (int a2 = 0; a2 < 4; ++a2)
#pragma unroll
        for (int k2 = 0; k2 < 2; ++k2)
            fr.acc[MH * 4 + a2][BI] =
                __builtin_amdgcn_mfma_f32_16x16x32_bf16(
                    af[a2][k2], bf[k2], fr.acc[MH * 4 + a2][BI], 0, 0, 0);
    __builtin_amdgcn_s_setprio(0);
}

// ---------------- 256x256 core — PIPELINED, reg-fitting (R14) ----------------
// Per K-tile t (buf = t&1), 4 clusters:
//   C0: rd bf<1>(t)->bfb   | MFMA Q(0,0): afP x bfa   | bar
//   C1: rd af<1>(t)->afQ   | MFMA Q(0,1): afP x bfb   | bar
//   C2:                      MFMA Q(1,0): afQ x bfa   <- bfa DEAD after this
//       [SB] stageB(t+2) ; vmcnt(4|0) ; bar
//   C3: rd af<0>(t+1)->afP, bf<0>(t+1)->bfa (overwrite)
//                            MFMA Q(1,1): afQ x bfb
//       [SB] stageA(t+2) ; bar
// Ledger (= R10's, HW-correct): prologue 16 loads, vm8 -> {A1,B1}=8.
// C2: +B(t+2)=12, vm4 -> {B(t+2)} => A(t+1),B(t+1) landed before C3's
// buf^1 reads (+barrier => all waves). C3: +A(t+2)=8 steady.
// WAR: stageB(t+2)->sB(buf): bfa consumed by C2's MFMA (lgkm) pre-C2-bar...
// (bfa was read from sB at the PREVIOUS C3, consumed at C0/C2; bfb read C0,
// consumed C1) — stageB issues after C1-end bar with both drained. Wait:
// stageB at C2 is after C1-end barrier; sB(buf) readers: bfa (read prev-C3,
// consumed C0's MFMA lgkm before C0-end bar) and bfb (read C0, consumed C1's
// MFMA before C1-end bar). OK. stageA(t+2)->sA(buf) at C3 (after C2-end
// bar): af0 read prev-C3 consumed C0/C1; af1 read C1 consumed C2's MFMA
// before C2-end bar. OK.
// Registers: frags afP32+afQ32+bfa16+bfb16 = 96 VGPR (+addr ~116) + 128
// AGPR = ~244 <= 256 -> no thrash (R10 carried 112 frag VGPR and thrashed).
// Numerics: per-acc-element k-order identical to un-pipelined core.
__device__ __forceinline__ void gemm_core_256(
    const u16* __restrict__ A, const u16* __restrict__ Bt,
    int K, int lda, int ldb, int row0, int col0, u16* sm, Acc256& fr)
{
    const int t    = threadIdx.x;
    const int lane = t & 63;
    const int wave = t >> 6;
    const int wr   = wave >> 2;
    const int wc   = wave & 3;
    const int lr   = lane & 15;
    const int srow = lane >> 3;
    const int gc   = (lane & 7) ^ srow;

    const u16* const sA0 = sm;
    const u16* const sA1 = sm + 16384;
    const u16* const sB0 = sm + 32768;
    const u16* const sB1 = sm + 49152;

#pragma unroll
    for (int a = 0; a < 8; ++a)
#pragma unroll
        for (int b = 0; b < 4; ++b)
            fr.acc[a][b] = (f32x4){0.f, 0.f, 0.f, 0.f};

    const u16* aB = A  + (long long)(row0 + wave * 8 + srow) * lda + gc * 8;
    const u16* bB = Bt + (long long)(col0 + wave * 8 + srow) * ldb + gc * 8;
    u16* const sAw = sm + wave * 512;
    u16* const sBw = sm + 32768 + wave * 512;

    auto stageA = [&](int kt) {
        u16* d = sAw + (kt & 1) * 16384;
        const u16* g = aB + kt * 64;
#pragma unroll
        for (int r4 = 0; r4 < 4; ++r4)
            gload16(g + (long long)(r4 * 64) * lda, d + r4 * 4096);
    };
    auto stageB = [&](int kt) {
        u16* d = sBw + (kt & 1) * 16384;
        const u16* g = bB + kt * 64;
#pragma unroll
        for (int r4 = 0; r4 < 4; ++r4)
            gload16(g + (long long)(r4 * 64) * ldb, d + r4 * 4096);
    };

    // prologue: stage tiles 0,1; wait tile0 (8 loads of tile1 remain)
    stageA(0); stageB(0); stageA(1); stageB(1);
    wait_vm8();
    bar();

    short8 afP[4][2], afQ[4][2], bfa[2][2], bfb[2][2];
    rd_a<0>(sA0, wr, lane, lr, afP);
    rd_b<0>(sB0, wc, lane, lr, bfa);

    const int NT = K >> 6;                       // K-tiles (even)
#pragma unroll 1
    for (int i = 0; i < NT; i += 2) {
        const bool more = (i + 2 < NT);

        // ======== tile i (buf0) ========
        rd_b<1>(sB0, wc, lane, lr, bfb);                     // C0
        mm_q<0, 0>(fr, afP, bfa);
        bar();

        rd_a<1>(sA0, wr, lane, lr, afQ);                     // C1
        mm_q<0, 1>(fr, afP, bfb);
        bar();

        mm_q<1, 0>(fr, afQ, bfa);                            // C2 (bfa dead)
        __builtin_amdgcn_sched_barrier(0);
        if (more) { stageB(i + 2); wait_vm4(); } else wait_vm0();
        bar();

        rd_a<0>(sA1, wr, lane, lr, afP);                     // C3
        rd_b<0>(sB1, wc, lane, lr, bfa);                     //  (overwrite bfa)
        mm_q<1, 1>(fr, afQ, bfb);
        __builtin_amdgcn_sched_barrier(0);
        if (more) stageA(i + 2);
        bar();

        // ======== tile i+1 (buf1) ========
        rd_b<1>(sB1, wc, lane, lr, bfb);                     // C0
        mm_q<0, 0>(fr, afP, bfa);
        bar();

        rd_a<1>(sA1, wr, lane, lr, afQ);                     // C1
        mm_q<0, 1>(fr, afP, bfb);
        bar();

        mm_q<1, 0>(fr, afQ, bfa);                            // C2 (bfa dead)
        __builtin_amdgcn_sched_barrier(0);
        if (more) { stageB(i + 3); wait_vm4(); } else wait_vm0();
        bar();

        if (more) {                                          // C3
            rd_a<0>(sA0, wr, lane, lr, afP);
            rd_b<0>(sB0, wc, lane, lr, bfa);
        }
        mm_q<1, 1>(fr, afQ, bfb);
        __builtin_amdgcn_sched_barrier(0);
        if (more) stageA(i + 3);
        bar();
    }
}

// ---------------- 256x192 core (qkv) — PIPELINED (R6 HW-pass) ---------------
__device__ __forceinline__ void gemm_core_192(
    const u16* __restrict__ A, const u16* __restrict__ Bt,
    int K, int lda, int ldb, int row0, int col0, u16* sm, Acc192& fr)
{
    const int t    = threadIdx.x;
    const int lane = t & 63;
    const int wave = t >> 6;
    const int wr   = wave >> 2;
    const int wc   = wave & 3;
    const int lr   = lane & 15;
    const int srow = lane >> 3;
    const int gc   = (lane & 7) ^ srow;

    const u16* const sA0 = sm;
    const u16* const sA1 = sm + 16384;
    const u16* const sB0 = sm + 32768;
    const u16* const sB1 = sm + 45056;

#pragma unroll
    for (int a = 0; a < 8; ++a)
#pragma unroll
        for (int b = 0; b < 3; ++b)
            fr.acc[a][b] = (f32x4){0.f, 0.f, 0.f, 0.f};

    const u16* aB = A  + (long long)(row0 + wave * 8 + srow) * lda + gc * 8;
    const u16* bB = Bt + (long long)(col0 + wave * 8 + srow) * ldb + gc * 8;
    u16* const sAw = sm + wave * 512;
    u16* const sBw = sm + 32768 + wave * 512;

    auto stageA = [&](int kt) {                  // 4 loads/wave
        u16* d = sAw + (kt & 1) * 16384;
        const u16* g = aB + kt * 64;
#pragma unroll
        for (int r4 = 0; r4 < 4; ++r4)
            gload16(g + (long long)(r4 * 64) * lda, d + r4 * 4096);
    };
    auto stageB = [&](int kt) {                  // 3 loads/wave (192 rows)
        u16* d = sBw + (kt & 1) * 12288;
        const u16* g = bB + kt * 64;
#pragma unroll
        for (int r4 = 0; r4 < 3; ++r4)
            gload16(g + (long long)(r4 * 64) * ldb, d + r4 * 4096);
    };

    stageA(0); stageB(0); stageA(1); stageB(1);
    wait_vm7();
    bar();

    short8 afP[4][2], afQ[4][2], bfaP[2][2], bfaQ[2][2], bfb[2];
    rd_a<0>(sA0, wr, lane, lr, afP);
    rd_b01(sB0, wc, lane, lr, bfaP);

    const int NT = K >> 6;                       // K-tiles (even)
#pragma unroll 1
    for (int i = 0; i < NT; i += 2) {
        const bool more = (i + 2 < NT);

        rd_b2(sB0, wc, lane, lr, bfb);                       // C0
        mm_b01<0>(fr, afP, bfaP);
        bar();

        rd_a<1>(sA0, wr, lane, lr, afQ);                     // C1
        mm_b2<0>(fr, afP, bfb);
        bar();

        mm_b2<1>(fr, afQ, bfb);                              // C2
        __builtin_amdgcn_sched_barrier(0);
        if (more) { stageB(i + 2); wait_vm3(); } else wait_vm0();
        bar();

        rd_a<0>(sA1, wr, lane, lr, afP);                     // C3
        rd_b01(sB1, wc, lane, lr, bfaQ);
        mm_b01<1>(fr, afQ, bfaP);
        __builtin_amdgcn_sched_barrier(0);
        if (more) stageA(i + 2);
        bar();

        rd_b2(sB1, wc, lane, lr, bfb);                       // C0
        mm_b01<0>(fr, afP, bfaQ);
        bar();

        rd_a<1>(sA1, wr, lane, lr, afQ);                     // C1
        mm_b2<0>(fr, afP, bfb);
        bar();

        mm_b2<1>(fr, afQ, bfb);                              // C2
        __builtin_amdgcn_sched_barrier(0);
        if (more) { stageB(i + 3); wait_vm3(); } else wait_vm0();
        bar();

        if (more) {                                          // C3
            rd_a<0>(sA0, wr, lane, lr, afP);
            rd_b01(sB0, wc, lane, lr, bfaP);
        }
        mm_b01<1>(fr, afQ, bfaQ);
        __builtin_amdgcn_sched_barrier(0);
        if (more) stageA(i + 3);
        bar();
    }
}

// ---------------- 256x128 core (pv) — PIPELINED (R11 HW-pass) ---------------
__device__ __forceinline__ void gemm_core_n128(
    const u16* __restrict__ A, const u16* __restrict__ Bt,
    int K, int lda, int ldb, int row0, int col0, u16* sm, Acc128& fr)
{
    const int t    = threadIdx.x;
    const int lane = t & 63;
    const int wave = t >> 6;
    const int wr   = wave >> 2;
    const int wc   = wave & 3;
    const int lr   = lane & 15;
    const int srow = lane >> 3;
    const int gc   = (lane & 7) ^ srow;

    const u16* const sA0 = sm;
    const u16* const sA1 = sm + 16384;
    const u16* const sB0 = sm + 32768;
    const u16* const sB1 = sm + 40960;

#pragma unroll
    for (int a = 0; a < 8; ++a)
#pragma unroll
        for (int b = 0; b < 2; ++b)
            fr.acc[a][b] = (f32x4){0.f, 0.f, 0.f, 0.f};

    const u16* aB = A  + (long long)(row0 + wave * 8 + srow) * lda + gc * 8;
    const u16* bB = Bt + (long long)(col0 + wave * 8 + srow) * ldb + gc * 8;
    u16* const sAw = sm + wave * 512;
    u16* const sBw = sm + 32768 + wave * 512;

    auto stageA = [&](int kt) {                  // 4 loads/wave (256 rows)
        u16* d = sAw + (kt & 1) * 16384;
        const u16* g = aB + kt * 64;
#pragma unroll
        for (int r4 = 0; r4 < 4; ++r4)
            gload16(g + (long long)(r4 * 64) * lda, d + r4 * 4096);
    };
    auto stageB = [&](int kt) {                  // 2 loads/wave (128 rows)
        u16* d = sBw + (kt & 1) * 8192;
        const u16* g = bB + kt * 64;
#pragma unroll
        for (int r4 = 0; r4 < 2; ++r4)
            gload16(g + (long long)(r4 * 64) * ldb, d + r4 * 4096);
    };

    // prologue: tiles 0,1 (6 loads each); guard tile0 with vmcnt(6)
    stageB(0); stageA(0); stageB(1); stageA(1);
    wait_vm6();
    bar();

    short8 afP[4][2], afQ[4][2], b0P[2], b0Q[2], bfb[2];
    rd_a<0>(sA0, wr, lane, lr, afP);
    rd_b1f<0>(sB0, wc, lane, lr, b0P);

    const int NT = K >> 6;                       // K-tiles (even; 32 here)
#pragma unroll 1
    for (int i = 0; i < NT; i += 2) {
        const bool more = (i + 2 < NT);

        // ======== tile i (buf0) ========
        rd_b1f<1>(sB0, wc, lane, lr, bfb);                   // C0
        mm_h<0, 0>(fr, afP, b0P);
        bar();

        rd_a<1>(sA0, wr, lane, lr, afQ);                     // C1
        mm_h<0, 1>(fr, afP, bfb);
        bar();

        mm_h<1, 1>(fr, afQ, bfb);                            // C2
        __builtin_amdgcn_sched_barrier(0);
        if (more) { stageB(i + 2); wait_vm2(); } else wait_vm0();
        bar();

        rd_a<0>(sA1, wr, lane, lr, afP);                     // C3
        rd_b1f<0>(sB1, wc, lane, lr, b0Q);
        mm_h<1, 0>(fr, afQ, b0P);
        __builtin_amdgcn_sched_barrier(0);
        if (more) stageA(i + 2);
        bar();

        // ======== tile i+1 (buf1) ========
        rd_b1f<1>(sB1, wc, lane, lr, bfb);                   // C0
        mm_h<0, 0>(fr, afP, b0Q);
        bar();

        rd_a<1>(sA1, wr, lane, lr, afQ);                     // C1
        mm_h<0, 1>(fr, afP, bfb);
        bar();

        mm_h<1, 1>(fr, afQ, bfb);                            // C2
        __builtin_amdgcn_sched_barrier(0);
        if (more) { stageB(i + 3); wait_vm2(); } else wait_vm0();
        bar();

        if (more) {                                          // C3
            rd_a<0>(sA0, wr, lane, lr, afP);
            rd_b1f<0>(sB0, wc, lane, lr, b0P);
        }
        mm_h<1, 0>(fr, afQ, b0Q);
        __builtin_amdgcn_sched_barrier(0);
        if (more) stageA(i + 3);
        bar();
    }
}

// C/D layout (16x16): col = lane&15, row = (lane>>4)*4 + reg   [m89/m91-verified]

// ---------- merged QKV projection, 256x192 pipelined, LINEAR dispatch -------
__global__ __launch_bounds__(512, 1) void gemm_qkv(
    const u16* __restrict__ Xb, const u16* __restrict__ Wb,
    u16* __restrict__ QK, u16* __restrict__ VT)
{
    __shared__ u16 sm[57344];          // 112 KiB
    const int row0 = blockIdx.y * 256;
    const int col0 = blockIdx.x * 192;

    Acc192 fr;
    gemm_core_192(Xb, Wb, 1024, 1024, 1024, row0, col0, sm, fr);

    const int lane = threadIdx.x & 63;
    const int wave = threadIdx.x >> 6;
    const int wr = wave >> 2, wc = wave & 3;
    const int cr = (lane >> 4) * 4, cc = lane & 15;

#pragma unroll
    for (int a = 0; a < 8; ++a) {
        const int grow = row0 + wr * 128 + a * 16 + cr;   // 4-aligned
#pragma unroll
        for (int b = 0; b < 3; ++b) {
            const int gcol = col0 + wc * 48 + b * 16 + cc;
            if (gcol < 2048) {
#pragma unroll
                for (int r = 0; r < 4; ++r)
                    QK[(long long)(grow + r) * 2048 + gcol] =
                        f32_to_bf16(fr.acc[a][b][r]);
            } else {
                const int bz = grow >> 11, s = grow & 2047;
                const int d = gcol - 2048;
                ushort4 o;
                o.x = f32_to_bf16(fr.acc[a][b][0]);
                o.y = f32_to_bf16(fr.acc[a][b][1]);
                o.z = f32_to_bf16(fr.acc[a][b][2]);
                o.w = f32_to_bf16(fr.acc[a][b][3]);
                *(ushort4*)(&VT[((long long)(bz * 1024 + d)) * 2048 + s]) = o;
            }
        }
    }
}

// ---------- S GEMM + fused unnormalized softmax (R14 pipelined 256 core) ----
// E[b] = exp(Q[b]*K[b]^T / 32). LINEAR dispatch (l atomicAdd ordering must
// match passing rounds — the R7/R8 failure channel).
__global__ __launch_bounds__(512, 1) void gemm_s_exp(
    const u16* __restrict__ QK, u16* __restrict__ E, float* __restrict__ l)
{
    __shared__ u16 sm[65536];
    const long long boff = (long long)blockIdx.z * 2048 * 2048;
    const u16* Q  = QK + boff;
    const u16* Kp = QK + boff + 1024;
    u16* Eb = E + boff;
    float* lb = l + (long long)blockIdx.z * 2048;
    const int row0 = blockIdx.y * 256;
    const int col0 = blockIdx.x * 256;

    Acc256 fr;
    gemm_core_256(Q, Kp, 1024, 2048, 2048, row0, col0, sm, fr);

    const int lane = threadIdx.x & 63;
    const int wave = threadIdx.x >> 6;
    const int wr = wave >> 2, wc = wave & 3;
    const int cr = (lane >> 4) * 4, cc = lane & 15;

#pragma unroll
    for (int a = 0; a < 8; ++a) {
        float rs[4] = {0.f, 0.f, 0.f, 0.f};
#pragma unroll
        for (int b = 0; b < 4; ++b)
#pragma unroll
            for (int r = 0; r < 4; ++r) {
                float e = __expf(fr.acc[a][b][r] * 0.03125f);
                rs[r] += e;
                int grow = row0 + wr * 128 + a * 16 + cr + r;
                int gcol = col0 + wc * 64 + b * 16 + cc;
                Eb[(long long)grow * 2048 + gcol] = f32_to_bf16(e);
            }
#pragma unroll
        for (int r = 0; r < 4; ++r) {
#pragma unroll
            for (int m = 1; m < 16; m <<= 1) rs[r] += __shfl_xor(rs[r], m, 64);
            if ((lane & 15) == 0)
                atomicAdd(&lb[row0 + wr * 128 + a * 16 + cr + r], rs[r]);
        }
    }
}

// ---------- PV GEMM + XCD chunking: out[q,d] = (E*VT^T)[q,d] / l[q] ----------
// (R12 measured: pv chunking won ~17us — E-panel L3 dedup. Kept.)
__global__ __launch_bounds__(512, 1) void gemm_pv(
    const u16* __restrict__ E, const u16* __restrict__ VT,
    const float* __restrict__ l, float* __restrict__ Y)
{
    __shared__ u16 sm[49152];          // 96 KiB
    const int lin = blockIdx.x + 8 * (blockIdx.y + 8 * blockIdx.z);  // [0,256)
    const int wid = (lin & 7) * 32 + (lin >> 3);         // XCD chunk (bijective)
    const int dy = wid & 7;            // d-tile (fastest -> same-XCD E sharing)
    const int qx = (wid >> 3) & 7;     // q-tile
    const int bz = wid >> 6;           // batch

    const u16* Eb  = E  + (long long)bz * 2048 * 2048;
    const u16* VTb = VT + (long long)bz * 1024 * 2048;
    const float* lb = l + (long long)bz * 2048;
    float* Yb = Y + (long long)bz * 2048 * 1024;
    const int row0 = qx * 256;   // q
    const int col0 = dy * 128;   // d

    Acc128 fr;
    gemm_core_n128(Eb, VTb, 2048, 2048, 2048, row0, col0, sm, fr);

    const int lane = threadIdx.x & 63;
    const int wave = threadIdx.x >> 6;
    const int wr = wave >> 2, wc = wave & 3;
    const int cr = (lane >> 4) * 4, cc = lane & 15;

#pragma unroll
    for (int a = 0; a < 8; ++a) {
        const int q0 = row0 + wr * 128 + a * 16 + cr;    // 4-aligned
        const float4 l4 = *(const float4*)(&lb[q0]);
        const float inv0 = 1.0f / l4.x, inv1 = 1.0f / l4.y;
        const float inv2 = 1.0f / l4.z, inv3 = 1.0f / l4.w;
#pragma unroll
        for (int b = 0; b < 2; ++b) {
            const int d = col0 + wc * 32 + b * 16 + cc;
            Yb[(long long)(q0 + 0) * 1024 + d] = fr.acc[a][b][0] * inv0;
            Yb[(long long)(q0 + 1) * 1024 + d] = fr.acc[a][b][1] * inv1;
            Yb[(long long)(q0 + 2) * 1024 + d] = fr.acc[a][b][2] * inv2;
            Yb[(long long)(q0 + 3) * 1024 + d] = fr.acc[a][b][3] * inv3;
        }
    }
}

// ---------- launch ----------
extern "C" void kernel_launch(void* const* d_in, const int* in_sizes, int n_in,
                              void* d_out, int out_size, void* d_ws, size_t ws_size,
                              hipStream_t stream) {
    const float* x = (const float*)d_in[0];   // [4,2048,1024]
    const float* W = (const float*)d_in[1];   // [3072,1024]
    float* out = (float*)d_out;               // [4,2048,1024]

    char* ws = (char*)d_ws;
    // layout (bytes): Xb 16.8M | Wb 6.3M | QK 33.6M | VT 16.8M | E 33.6M | l 32K
    u16*   Xb = (u16*)(ws);
    u16*   Wb = (u16*)(ws + 16777216LL);
    u16*   QK = (u16*)(ws + 23068672LL);
    u16*   VT = (u16*)(ws + 56623104LL);
    u16*   E  = (u16*)(ws + 73400320LL);
    float* l  = (float*)(ws + 106954752LL);

    const int nx4 = 8192 * 1024 / 4, nw4 = 3072 * 1024 / 4;
    cast_inputs<<<11296, 256, 0, stream>>>(x, Xb, W, Wb, l, nx4, nw4, 8192);
    gemm_qkv<<<dim3(16, 32, 1), 512, 0, stream>>>(Xb, Wb, QK, VT);
    gemm_s_exp<<<dim3(8, 8, 4), 512, 0, stream>>>(QK, E, l);
    gemm_pv<<<dim3(8, 8, 4), 512, 0, stream>>>(E, VT, l, out);
}